// Round 18
// baseline (81.403 us; speedup 1.0000x reference)
//
#include <hip/hip_runtime.h>
#include <hip/hip_bf16.h>
#include <stdint.h>

#define NB    32
#define CIN   128
#define HIN   56
#define HW    (HIN*HIN)     // 3136
#define OCH   256
#define OHW   54
#define SPB   (OHW*OHW)     // 2916
#define KSZ   (CIN*9)       // 1152 = GEMM K
#define BM    256           // oc rows per block (= OCH)
#define BN    192           // flattened (n,sp) cols; 93312/192 = 486 exact
#define BK    64
#define NKS   (KSZ/BK)      // 18 K-tiles
#define TOTC  (NB*SPB)      // 93312
#define NT    486
#define GRAN  ((BM+BN)*8)   // 3584 granules (16B) per buffer = 56KB

#define XPB   (98*4*NB)       // 12544 xpose blocks
#define WCB   ((OCH*KSZ)/256) // 1152 wcast blocks

typedef __attribute__((ext_vector_type(8))) short bf16x8;
typedef __attribute__((ext_vector_type(4))) float f32x4;

typedef __attribute__((address_space(1))) const uint32_t g_u32;
typedef __attribute__((address_space(3))) uint32_t l_u32;
static __device__ __forceinline__ void gl_lds16(const void* g, void* l) {
    __builtin_amdgcn_global_load_lds((g_u32*)g, (l_u32*)l, 16, 0, 0);
}

// ---- fused pre-pass: x NCHW f32 -> NHWC bf16  +  w OIHW f32 -> packed bf16 ----
__global__ void prep(const float* __restrict__ x, __hip_bfloat16* __restrict__ xt,
                     const float* __restrict__ w, __hip_bfloat16* __restrict__ wt) {
    __shared__ float tile[32][33];
    const int bid = blockIdx.x;
    const int t = threadIdx.x;
    if (bid < XPB) {
        const int hwb = bid % 98;
        const int cb  = (bid / 98) & 3;
        const int n   = bid / 392;
        const int hw0 = hwb * 32, c0 = cb * 32;
        const int tx = t & 31, ty = t >> 5;
        const float* xp = x + ((size_t)n*CIN + c0)*HW + hw0;
        #pragma unroll
        for (int i = ty; i < 32; i += 8)
            tile[i][tx] = xp[(size_t)i*HW + tx];
        __syncthreads();
        const int hwl = t >> 3, q = t & 7;
        ushort4 v;
        v.x = __bfloat16_as_ushort(__float2bfloat16(tile[q*4+0][hwl]));
        v.y = __bfloat16_as_ushort(__float2bfloat16(tile[q*4+1][hwl]));
        v.z = __bfloat16_as_ushort(__float2bfloat16(tile[q*4+2][hwl]));
        v.w = __bfloat16_as_ushort(__float2bfloat16(tile[q*4+3][hwl]));
        __hip_bfloat16* op = xt + ((size_t)n*HW + hw0 + hwl)*CIN + c0 + q*4;
        *(ushort4*)op = v;
    } else {
        int tid = (bid - XPB)*256 + t;           // < OCH*KSZ exactly
        int oc = tid / KSZ, r = tid % KSZ;
        int pos = r >> 7, ic = r & 127;
        wt[tid] = __float2bfloat16(w[((size_t)(oc*CIN + ic))*9 + pos]);
    }
}

// ---- main: implicit-GEMM bf16 MFMA conv (round-9 config + 2-phase epilogue) ----
// grid (486), block 512 = 8 waves (2M x 4N), per-wave 128x48.
// BK=64, DOUBLE buffer (2 x 56KB), ONE barrier + vmcnt(0)-certify per K-tile
// (stages issued ~3/4 tile before the certify); free-running waves with
// own-wave counted lgkm splits. LDS layout per buffer:
// [A rows 0..255 | B rows 0..191] x 8 granules/row, slot j = k-chunk j^(row&7).
__global__ __launch_bounds__(512, 2)
void conv_mfma(const __hip_bfloat16* __restrict__ xt,
               const __hip_bfloat16* __restrict__ wt,
               const float* __restrict__ bias,
               float* __restrict__ out) {
    __shared__ uint4 smem[2*GRAN];   // 114688 B

    const int t = threadIdx.x;
    // bijective XCD swizzle: nwg=486 = 8*60+6 -> q=60, r=6
    const int orig = blockIdx.x;
    const int xcd = orig & 7;
    const int tile = (xcd < 6 ? xcd*61 : 6*61 + (xcd-6)*60) + (orig >> 3);

    const int lane = t & 63, wid = t >> 6;
    const int wm = wid >> 2, wn = wid & 3;     // per-wave 128 rows x 48 cols
    const int lr = lane & 15, lq = lane >> 4;

    // staging sources: A granules q = i*512+t (i<4); B q = i*512+t (i<3)
    const __hip_bfloat16* aptr[4];
    #pragma unroll
    for (int i = 0; i < 4; ++i) {
        int q = i*512 + t;
        int row = q >> 3, j = q & 7;
        int ls = j ^ (row & 7);
        aptr[i] = wt + (size_t)row*KSZ + ls*8;
    }
    const __hip_bfloat16* bptr[3];
    #pragma unroll
    for (int i = 0; i < 3; ++i) {
        int q = i*512 + t;
        int row = q >> 3, j = q & 7;
        int ls = j ^ (row & 7);
        int colg = tile*BN + row;              // exact tiling: always < TOTC
        int n = colg / SPB, rem = colg - n*SPB;
        int oh = rem / OHW, ow = rem - oh*OHW;
        bptr[i] = xt + ((size_t)(n*HIN + oh)*HIN + ow)*CIN + ls*8;
    }

    auto issueT = [&](int ks) {      // 7 gl_lds: full tile ks -> buf[ks&1]
        uint4* dst = smem + (ks & 1)*GRAN;
        const int aoff = ks*BK;
        const int pos = ks >> 1;
        const int kh = pos / 3, kw = pos - kh*3;
        const int boff = (kh*HIN + kw)*CIN + (ks & 1)*64;
        #pragma unroll
        for (int i = 0; i < 4; ++i) gl_lds16(aptr[i] + aoff, dst + i*512 + t);
        #pragma unroll
        for (int i = 0; i < 3; ++i) gl_lds16(bptr[i] + boff, dst + 2048 + i*512 + t);
    };

    // per-lane read offsets (granule units), kk=0; kk=1 is ^4 (flips slot bit 2)
    int ao[8], bo[3];
    #pragma unroll
    for (int mi = 0; mi < 8; ++mi) {
        int ra = wm*128 + mi*16 + lr;
        ao[mi] = ra*8 + (lq ^ (ra & 7));
    }
    #pragma unroll
    for (int ni = 0; ni < 3; ++ni) {
        int rb = wn*48 + ni*16 + lr;
        bo[ni] = 2048 + rb*8 + (lq ^ (rb & 7));
    }

    f32x4 acc[8][3];
    #pragma unroll
    for (int i = 0; i < 8; ++i)
        #pragma unroll
        for (int j = 0; j < 3; ++j)
            acc[i][j] = (f32x4){0.f, 0.f, 0.f, 0.f};

    #define MFMA_BF16 __builtin_amdgcn_mfma_f32_16x16x32_bf16
    #define MFMA12(AARR, MIB, BARR) \
        __builtin_amdgcn_s_setprio(1); \
        _Pragma("unroll") \
        for (int ii = 0; ii < 4; ++ii) \
            _Pragma("unroll") \
            for (int ni = 0; ni < 3; ++ni) \
                acc[(MIB)+ii][ni] = MFMA_BF16(AARR[ii], BARR[ni], acc[(MIB)+ii][ni], 0, 0, 0); \
        __builtin_amdgcn_s_setprio(0);

    // prologue: tile 0 staged and certified
    issueT(0);
    asm volatile("s_waitcnt vmcnt(0)" ::: "memory");
    __builtin_amdgcn_s_barrier();
    __builtin_amdgcn_sched_barrier(0);

    for (int ks = 0; ks < NKS; ++ks) {
        const uint4* buf = smem + (ks & 1)*GRAN;
        bf16x8 a[4], a2[4], b[3];

        // ---- kk=0 ----
        #pragma unroll
        for (int mi = 0; mi < 4; ++mi) a[mi] = *(bf16x8*)&buf[ao[mi]];
        #pragma unroll
        for (int ni = 0; ni < 3; ++ni) b[ni] = *(bf16x8*)&buf[bo[ni]];
        if (ks + 1 < NKS) issueT(ks + 1);          // ~3/4-tile flight before certify
        #pragma unroll
        for (int mi = 0; mi < 4; ++mi) a2[mi] = *(bf16x8*)&buf[ao[4 + mi]];

        asm volatile("s_waitcnt lgkmcnt(4)" ::: "memory");   // a,b done
        __builtin_amdgcn_sched_barrier(0);
        MFMA12(a, 0, b)
        asm volatile("s_waitcnt lgkmcnt(0)" ::: "memory");   // a2 done
        __builtin_amdgcn_sched_barrier(0);
        MFMA12(a2, 4, b)

        // ---- kk=1 ----
        #pragma unroll
        for (int mi = 0; mi < 4; ++mi) a[mi] = *(bf16x8*)&buf[ao[mi] ^ 4];
        #pragma unroll
        for (int ni = 0; ni < 3; ++ni) b[ni] = *(bf16x8*)&buf[bo[ni] ^ 4];
        #pragma unroll
        for (int mi = 0; mi < 4; ++mi) a2[mi] = *(bf16x8*)&buf[ao[4 + mi] ^ 4];

        asm volatile("s_waitcnt lgkmcnt(4)" ::: "memory");
        __builtin_amdgcn_sched_barrier(0);
        MFMA12(a, 0, b)
        asm volatile("s_waitcnt lgkmcnt(0)" ::: "memory");
        __builtin_amdgcn_sched_barrier(0);
        MFMA12(a2, 4, b)

        // boundary: certify buf[(ks+1)&1] (stages landed long ago), one barrier
        if (ks + 1 < NKS) {
            asm volatile("s_waitcnt vmcnt(0)" ::: "memory");
            __builtin_amdgcn_s_barrier();
            __builtin_amdgcn_sched_barrier(0);
        }
    }

    __syncthreads();

    // --- epilogue v2: [128][196] restage (100KB), 2 phases, ALL 512 threads store
    // linear f4 index: f = pass*512 + t, row = f/48, col = (f%48)*4 -> each wave
    // issues <=2 contiguous 16B-store segments; 3 barriers total (was 8).
    float (*eps)[196] = (float (*)[196])smem;
    #pragma unroll
    for (int h = 0; h < 2; ++h) {
        if (wm == h) {
            #pragma unroll
            for (int mi = 0; mi < 8; ++mi) {
                int rl = mi*16 + lq*4;
                #pragma unroll
                for (int ni = 0; ni < 3; ++ni) {
                    int cl = wn*48 + ni*16 + lr;
                    #pragma unroll
                    for (int r = 0; r < 4; ++r)
                        eps[rl + r][cl] = acc[mi][ni][r];
                }
            }
        }
        __syncthreads();
        #pragma unroll
        for (int pass = 0; pass < 12; ++pass) {
            int f = pass*512 + t;          // 0..6143
            int rr = f / 48;               // 0..127
            int cc = (f - rr*48) * 4;      // 0..188
            int colg = tile*BN + cc;       // < TOTC (exact tiling)
            int nn = colg / SPB;
            int sp = colg - nn*SPB;        // SPB%4==0 -> 4-col group never straddles
            int rg = h*128 + rr;
            f32x4 v = *(f32x4*)&eps[rr][cc];
            v = v + bias[rg];
            *(f32x4*)&out[((size_t)nn*OCH + rg)*SPB + sp] = v;
        }
        if (h == 0) __syncthreads();       // before phase-1 overwrites eps
    }
}

// ---- fallback: direct fp32 conv ----
__global__ void conv_naive(const float* __restrict__ x, const float* __restrict__ w,
                           const float* __restrict__ bias, float* __restrict__ out) {
    size_t tid = (size_t)blockIdx.x*256 + threadIdx.x;
    const size_t total = (size_t)NB*OCH*SPB;
    if (tid >= total) return;
    int col = (int)(tid % SPB);
    int oc  = (int)((tid / SPB) % OCH);
    int n   = (int)(tid / ((size_t)SPB*OCH));
    int oh = col / OHW, ow = col % OHW;
    float s = bias[oc];
    for (int ic = 0; ic < CIN; ++ic)
        #pragma unroll
        for (int kh = 0; kh < 3; ++kh)
            #pragma unroll
            for (int kw = 0; kw < 3; ++kw)
                s += x[((size_t)(n*CIN+ic)*HIN + oh+kh)*HIN + ow+kw]
                   * w[((size_t)(oc*CIN+ic)*3 + kh)*3 + kw];
    out[tid] = s;
}

extern "C" void kernel_launch(void* const* d_in, const int* in_sizes, int n_in,
                              void* d_out, int out_size, void* d_ws, size_t ws_size,
                              hipStream_t stream) {
    const float* x    = (const float*)d_in[0];
    const float* w    = (const float*)d_in[1];
    const float* bias = (const float*)d_in[2];
    float* out = (float*)d_out;

    const size_t xt_bytes = (size_t)NB*HW*CIN*sizeof(__hip_bfloat16);
    const size_t wt_bytes = (size_t)OCH*KSZ*sizeof(__hip_bfloat16);

    if (ws_size >= xt_bytes + wt_bytes) {
        __hip_bfloat16* xt  = (__hip_bfloat16*)d_ws;
        __hip_bfloat16* wtp = (__hip_bfloat16*)((char*)d_ws + xt_bytes);
        hipLaunchKernelGGL(prep, dim3(XPB + WCB), dim3(256), 0, stream, x, xt, w, wtp);
        hipLaunchKernelGGL(conv_mfma, dim3(NT), dim3(512), 0, stream, xt, wtp, bias, out);
    } else {
        size_t total = (size_t)NB*OCH*SPB;
        hipLaunchKernelGGL(conv_naive, dim3((unsigned)((total + 255)/256)), dim3(256), 0, stream,
                           x, w, bias, out);
    }
}